// Round 5
// baseline (75.014 us; speedup 1.0000x reference)
//
#include <hip/hip_runtime.h>
#include <stdint.h>
#include <math.h>

// Problem constants (fixed by the reference)
#define BATCH 8
#define HH 2048
#define WW 2048
#define R 16                          // rows per chunk
#define NSTRIPS (HH / R)              // 128
#define NBLK (NSTRIPS * BATCH)        // 1024 chunks == 1024 blocks
#define CHUNK_DWORDS (R * WW / 32)    // 1024 mask dwords per chunk (4 KB LDS)
#define MAXK 2000000
#define TAIL_I4 (MAXK / 4)            // 500000 int4 slots in each output plane
#define TAIL_PER_BLK ((TAIL_I4 + NBLK - 1) / NBLK)  // 489

#define STAT_AGG (1u << 30)
#define STAT_INC (2u << 30)
#define VALMASK  0x3FFFFFFFu

// One block per chunk. Phases:
//  0) ticket -> virtual block id (decouples lookback from dispatch order)
//  1) 5x5 separable local-max, register-rolling, mask bytes -> LDS only
//  2) per-chunk popcount -> publish (STAT_AGG | agg) to flags[chunk]
//  3) wave-0 decoupled lookback (64 predecessors/hop) -> exclusive prefix,
//     publish (STAT_INC | inclusive)
//  4) ordered scatter of (h, w) at chunk_base + block-local rank
//  5) spin on flags[NBLK-1] inclusive -> grand total; fill this block's
//     1/NBLK slice of the -1 tail [total, MAXK) in both planes.
__global__ __launch_bounds__(256) void nms_fused(const float* __restrict__ scores,
                                                 uint32_t* __restrict__ flags,  // [NBLK+1], zeroed per call
                                                 int* __restrict__ out_h,
                                                 int* __restrict__ out_w) {
    __shared__ uint32_t lds_mask[CHUNK_DWORDS];  // 4 KB
    __shared__ int wsum[4];
    __shared__ int bcast[2];                     // [0]=chunk_base, [1]=total
    __shared__ int vbid_s;

    const int tid  = threadIdx.x;
    const int lane = tid & 63;
    const int wv   = tid >> 6;

    // ---- phase 0: ticket ----
    if (tid == 0) vbid_s = (int)atomicAdd(&flags[NBLK], 1u);
    __syncthreads();
    const int chunk = vbid_s;

    const int b     = chunk >> 7;            // / NSTRIPS (=128)
    const int strip = chunk & (NSTRIPS - 1);
    const int h0    = strip * R;
    const int c0    = wv * 512 + lane * 8;   // first owned column
    const float* img  = scores + (size_t)b * HH * WW;
    const float* colp = img + c0;
    const bool has_l = (c0 != 0);
    const bool has_r = (c0 != WW - 8);

    // ---- phase 1: mask gen (register rolling window) ----
    float win[5][12];  // columns c0-2 .. c0+9

#define LOAD_ROW(PH, hrow)                                                    \
    do {                                                                      \
        const int h_ = (hrow);                                                \
        if ((unsigned)h_ < (unsigned)HH) {                                    \
            const float* p_ = colp + (size_t)h_ * WW;                         \
            float4 a_ = *(const float4*)(p_);                                 \
            float4 b_ = *(const float4*)(p_ + 4);                             \
            win[PH][2] = a_.x; win[PH][3] = a_.y;                             \
            win[PH][4] = a_.z; win[PH][5] = a_.w;                             \
            win[PH][6] = b_.x; win[PH][7] = b_.y;                             \
            win[PH][8] = b_.z; win[PH][9] = b_.w;                             \
            if (has_l) {                                                      \
                float2 hl_ = *(const float2*)(p_ - 2);                        \
                win[PH][0] = hl_.x; win[PH][1] = hl_.y;                       \
            } else { win[PH][0] = -INFINITY; win[PH][1] = -INFINITY; }        \
            if (has_r) {                                                      \
                float2 hr_ = *(const float2*)(p_ + 8);                        \
                win[PH][10] = hr_.x; win[PH][11] = hr_.y;                     \
            } else { win[PH][10] = -INFINITY; win[PH][11] = -INFINITY; }      \
        } else {                                                              \
            _Pragma("unroll")                                                 \
            for (int k_ = 0; k_ < 12; ++k_) win[PH][k_] = -INFINITY;          \
        }                                                                     \
    } while (0)

    LOAD_ROW(0, h0 - 2);
    LOAD_ROW(1, h0 - 1);
    LOAD_ROW(2, h0 + 0);
    LOAD_ROW(3, h0 + 1);

    uint8_t* mbytes = (uint8_t*)lds_mask;
    const int bytecol = wv * 64 + lane;  // 0..255

#pragma unroll
    for (int i = 0; i < R; ++i) {
        LOAD_ROW((4 + i) % 5, h0 + 2 + i);
        const int CEN = (2 + i) % 5;

        float v[12];
#pragma unroll
        for (int k = 0; k < 12; ++k)
            v[k] = fmaxf(fmaxf(fmaxf(win[0][k], win[1][k]),
                               fmaxf(win[2][k], win[3][k])), win[4][k]);
        float p[11];
#pragma unroll
        for (int k = 0; k < 11; ++k) p[k] = fmaxf(v[k], v[k + 1]);

        uint32_t byte = 0;
#pragma unroll
        for (int j = 0; j < 8; ++j) {
            const float hm = fmaxf(fmaxf(p[j], p[j + 2]), v[j + 4]);
            const float s  = win[CEN][j + 2];
            if ((s == hm) && (s > 0.0f)) byte |= (1u << j);
        }
        mbytes[i * 256 + bytecol] = (uint8_t)byte;
    }
#undef LOAD_ROW

    __syncthreads();

    // ---- phase 2: per-thread 4 dwords, block reduce -> aggregate ----
    const uint4 m = ((const uint4*)lds_mask)[tid];
    const int pc = __popc(m.x) + __popc(m.y) + __popc(m.z) + __popc(m.w);

    int red = pc;
#pragma unroll
    for (int d = 32; d >= 1; d >>= 1) red += __shfl_down(red, d, 64);
    if (lane == 0) wsum[wv] = red;
    __syncthreads();
    const int agg = wsum[0] + wsum[1] + wsum[2] + wsum[3];

    if (tid == 0) atomicExch(&flags[chunk], STAT_AGG | (uint32_t)agg);

    // ---- phase 3: decoupled lookback (wave 0 only) ----
    if (wv == 0) {
        int exclusive = 0;
        int look = chunk;
        while (look > 0) {
            const int j = look - 1 - lane;  // lane 0 = nearest predecessor
            const bool valid = (j >= 0);
            uint32_t f;
            for (;;) {
                f = valid ? atomicOr(&flags[j], 0u) : STAT_INC;  // j<0 => inclusive 0
                if (!__any((f >> 30) == 0)) break;
                __builtin_amdgcn_s_sleep(1);
            }
            const unsigned long long m2 = __ballot((f >> 30) == 2);
            if (m2) {
                const int stop = (int)__ffsll((unsigned long long)m2) - 1;
                int c = (lane <= stop) ? (int)(f & VALMASK) : 0;
#pragma unroll
                for (int d = 1; d < 64; d <<= 1) c += __shfl_xor(c, d, 64);
                exclusive += c;
                break;
            } else {
                int c = (int)(f & VALMASK);  // all lanes valid aggregates here
#pragma unroll
                for (int d = 1; d < 64; d <<= 1) c += __shfl_xor(c, d, 64);
                exclusive += c;
                look -= 64;
            }
        }
        if (lane == 0) {
            bcast[0] = exclusive;
            atomicExch(&flags[chunk], STAT_INC | (uint32_t)(exclusive + agg));
        }
    }
    __syncthreads();
    const int chunk_base = bcast[0];

    // ---- phase 4: block exclusive scan + ordered scatter ----
    int incl = pc;
#pragma unroll
    for (int d = 1; d < 64; d <<= 1) {
        int n = __shfl_up(incl, d, 64);
        if (lane >= d) incl += n;
    }
    if (lane == 63) wsum[wv] = incl;   // safe: agg consumed before prior barrier
    __syncthreads();
    int wbase = 0;
    for (int i = 0; i < wv; ++i) wbase += wsum[i];

    int off = chunk_base + wbase + (incl - pc);

    uint32_t words[4] = {m.x, m.y, m.z, m.w};
    const uint32_t local0 = (uint32_t)tid * 128u;  // tid*4 dwords * 32 bits
#pragma unroll
    for (int wj = 0; wj < 4; ++wj) {
        uint32_t mm = words[wj];
        const uint32_t lb = local0 + (uint32_t)wj * 32u;
        while (mm) {
            const int bit = __ffs(mm) - 1;
            mm &= mm - 1;
            const uint32_t L = lb + (uint32_t)bit;  // bit index within chunk
            if (off < MAXK) {
                out_h[off] = h0 + (int)(L >> 11);
                out_w[off] = (int)(L & 2047u);
            }
            ++off;
        }
    }

    // ---- phase 5: grand total + this block's tail slice ----
    if (tid == 0) {
        uint32_t f;
        for (;;) {
            f = atomicOr(&flags[NBLK - 1], 0u);
            if ((f >> 30) == 2) break;
            __builtin_amdgcn_s_sleep(2);
        }
        int t = (int)(f & VALMASK);
        if (t > MAXK) t = MAXK;
        bcast[1] = t;
    }
    __syncthreads();
    const int total = bcast[1];

    const int i4base = chunk * TAIL_PER_BLK;
    for (int t = tid; t < TAIL_PER_BLK; t += 256) {
        const int i4 = i4base + t;
        if (i4 >= TAIL_I4) break;
        const int base = i4 * 4;
        if (base + 4 <= total) continue;  // fully covered by scatter
        if (base >= total) {
            const int4 neg = make_int4(-1, -1, -1, -1);
            *(int4*)(out_h + base) = neg;
            *(int4*)(out_w + base) = neg;
        } else {
#pragma unroll
            for (int j = 0; j < 4; ++j) {
                const int idx = base + j;
                if (idx >= total) { out_h[idx] = -1; out_w[idx] = -1; }
            }
        }
    }
}

extern "C" void kernel_launch(void* const* d_in, const int* in_sizes, int n_in,
                              void* d_out, int out_size, void* d_ws, size_t ws_size,
                              hipStream_t stream) {
    const float* scores = (const float*)d_in[0];
    int* out = (int*)d_out;
    uint32_t* flags = (uint32_t*)d_ws;  // [NBLK] status words + [NBLK] ticket

    // Zero flags + ticket every call (ws is not re-poisoned between replays;
    // this makes every replay identical and the lookback protocol valid).
    hipMemsetAsync(flags, 0, (size_t)(NBLK + 1) * sizeof(uint32_t), stream);

    nms_fused<<<NBLK, 256, 0, stream>>>(scores, flags, out, out + MAXK);
}

// Round 6
// 69.982 us; speedup vs baseline: 1.0719x; 1.0719x over previous
//
#include <hip/hip_runtime.h>
#include <stdint.h>
#include <math.h>

// Problem constants (fixed by the reference)
#define BATCH 8
#define HH 2048
#define WW 2048
#define R 16                          // rows per chunk
#define NSTRIPS (HH / R)              // 128
#define NBLK (NSTRIPS * BATCH)        // 1024 chunks == 1024 blocks
#define CHUNK_DWORDS (R * WW / 32)    // 1024 mask dwords per chunk (4 KB LDS)
#define MAXK 2000000

#define STAT_AGG (1u << 30)
#define STAT_INC (2u << 30)
#define VALMASK  0x3FFFFFFFu

// ---------------- Pass 0: prefill output with -1, zero flags ---------------
// Grid-stride int4 fill: 16 MB in ~3 us (the runtime fillBuffer kernel is
// latency-bound at 9% occupancy -- measured rounds 2/3). Block 0 also zeroes
// the NBLK+1 flag/ticket words so no hipMemsetAsync is needed.
__global__ __launch_bounds__(256) void prefill(int* __restrict__ out,
                                               uint32_t* __restrict__ flags) {
    const int4 neg = make_int4(-1, -1, -1, -1);
    const int stride = (int)(gridDim.x * 256);
    for (int i = (int)(blockIdx.x * 256 + threadIdx.x); i < (2 * MAXK) / 4; i += stride)
        ((int4*)out)[i] = neg;
    if (blockIdx.x == 0) {
        for (int i = threadIdx.x; i <= NBLK; i += 256) flags[i] = 0;
    }
}

// ---------------- Pass 1: fused mask + decoupled-lookback compaction -------
// One block per chunk (16 rows x 2048). No global-total dependency: the tail
// is already -1 from prefill; scatter overwrites the head [0, total).
__global__ __launch_bounds__(256) void nms_fused(const float* __restrict__ scores,
                                                 uint32_t* __restrict__ flags,  // [NBLK] status + [NBLK] ticket
                                                 int* __restrict__ out_h,
                                                 int* __restrict__ out_w) {
    __shared__ uint32_t lds_mask[CHUNK_DWORDS];  // 4 KB
    __shared__ int wsum[4];
    __shared__ int bcast0;
    __shared__ int vbid_s;

    const int tid  = threadIdx.x;
    const int lane = tid & 63;
    const int wv   = tid >> 6;

    // ---- ticket -> virtual chunk id (lookback predecessors are running) ----
    if (tid == 0) vbid_s = (int)atomicAdd(&flags[NBLK], 1u);
    __syncthreads();
    const int chunk = vbid_s;

    const int b     = chunk >> 7;            // / NSTRIPS (=128)
    const int strip = chunk & (NSTRIPS - 1);
    const int h0    = strip * R;
    const int c0    = wv * 512 + lane * 8;   // first owned column
    const float* colp = scores + (size_t)b * HH * WW + c0;
    const bool has_l = (c0 != 0);
    const bool has_r = (c0 != WW - 8);

    // ---- mask gen: register-rolling 5-row window ----
    float win[5][12];  // columns c0-2 .. c0+9

#define LOAD_ROW(PH, hrow)                                                    \
    do {                                                                      \
        const int h_ = (hrow);                                                \
        if ((unsigned)h_ < (unsigned)HH) {                                    \
            const float* p_ = colp + (size_t)h_ * WW;                         \
            float4 a_ = *(const float4*)(p_);                                 \
            float4 b_ = *(const float4*)(p_ + 4);                             \
            win[PH][2] = a_.x; win[PH][3] = a_.y;                             \
            win[PH][4] = a_.z; win[PH][5] = a_.w;                             \
            win[PH][6] = b_.x; win[PH][7] = b_.y;                             \
            win[PH][8] = b_.z; win[PH][9] = b_.w;                             \
            if (has_l) {                                                      \
                float2 hl_ = *(const float2*)(p_ - 2);                        \
                win[PH][0] = hl_.x; win[PH][1] = hl_.y;                       \
            } else { win[PH][0] = -INFINITY; win[PH][1] = -INFINITY; }        \
            if (has_r) {                                                      \
                float2 hr_ = *(const float2*)(p_ + 8);                        \
                win[PH][10] = hr_.x; win[PH][11] = hr_.y;                     \
            } else { win[PH][10] = -INFINITY; win[PH][11] = -INFINITY; }      \
        } else {                                                              \
            _Pragma("unroll")                                                 \
            for (int k_ = 0; k_ < 12; ++k_) win[PH][k_] = -INFINITY;          \
        }                                                                     \
    } while (0)

    LOAD_ROW(0, h0 - 2);
    LOAD_ROW(1, h0 - 1);
    LOAD_ROW(2, h0 + 0);
    LOAD_ROW(3, h0 + 1);

    uint8_t* mbytes = (uint8_t*)lds_mask;
    const int bytecol = wv * 64 + lane;  // 0..255

#pragma unroll
    for (int i = 0; i < R; ++i) {
        LOAD_ROW((4 + i) % 5, h0 + 2 + i);
        const int CEN = (2 + i) % 5;

        float v[12];
#pragma unroll
        for (int k = 0; k < 12; ++k)
            v[k] = fmaxf(fmaxf(fmaxf(win[0][k], win[1][k]),
                               fmaxf(win[2][k], win[3][k])), win[4][k]);
        float p[11];
#pragma unroll
        for (int k = 0; k < 11; ++k) p[k] = fmaxf(v[k], v[k + 1]);

        uint32_t byte = 0;
#pragma unroll
        for (int j = 0; j < 8; ++j) {
            const float hm = fmaxf(fmaxf(p[j], p[j + 2]), v[j + 4]);
            const float s  = win[CEN][j + 2];
            if ((s == hm) && (s > 0.0f)) byte |= (1u << j);
        }
        mbytes[i * 256 + bytecol] = (uint8_t)byte;
    }
#undef LOAD_ROW

    __syncthreads();

    // ---- per-thread 4 dwords (transposed via LDS), block reduce ----
    const uint4 m = ((const uint4*)lds_mask)[tid];
    const int pc = __popc(m.x) + __popc(m.y) + __popc(m.z) + __popc(m.w);

    int red = pc;
#pragma unroll
    for (int d = 32; d >= 1; d >>= 1) red += __shfl_down(red, d, 64);
    if (lane == 0) wsum[wv] = red;
    __syncthreads();
    const int agg = wsum[0] + wsum[1] + wsum[2] + wsum[3];

    if (tid == 0) atomicExch(&flags[chunk], STAT_AGG | (uint32_t)agg);

    // ---- decoupled lookback (wave 0 only, 64 predecessors per hop) ----
    if (wv == 0) {
        int exclusive = 0;
        int look = chunk;
        while (look > 0) {
            const int j = look - 1 - lane;  // lane 0 = nearest predecessor
            const bool valid = (j >= 0);
            uint32_t f;
            for (;;) {
                f = valid ? atomicOr(&flags[j], 0u) : STAT_INC;  // j<0 => inclusive 0
                if (!__any((f >> 30) == 0)) break;
                __builtin_amdgcn_s_sleep(1);
            }
            const unsigned long long m2 = __ballot((f >> 30) == 2);
            if (m2) {
                const int stop = (int)__ffsll((unsigned long long)m2) - 1;
                int c = (lane <= stop) ? (int)(f & VALMASK) : 0;
#pragma unroll
                for (int d = 1; d < 64; d <<= 1) c += __shfl_xor(c, d, 64);
                exclusive += c;
                break;
            } else {
                int c = (int)(f & VALMASK);
#pragma unroll
                for (int d = 1; d < 64; d <<= 1) c += __shfl_xor(c, d, 64);
                exclusive += c;
                look -= 64;
            }
        }
        if (lane == 0) {
            bcast0 = exclusive;
            atomicExch(&flags[chunk], STAT_INC | (uint32_t)(exclusive + agg));
        }
    }
    __syncthreads();
    const int chunk_base = bcast0;

    // ---- block exclusive scan + ordered scatter ----
    int incl = pc;
#pragma unroll
    for (int d = 1; d < 64; d <<= 1) {
        int n = __shfl_up(incl, d, 64);
        if (lane >= d) incl += n;
    }
    if (lane == 63) wsum[wv] = incl;  // safe: agg consumed before prior barrier
    __syncthreads();
    int wbase = 0;
    for (int i = 0; i < wv; ++i) wbase += wsum[i];

    int off = chunk_base + wbase + (incl - pc);

    uint32_t words[4] = {m.x, m.y, m.z, m.w};
    const uint32_t local0 = (uint32_t)tid * 128u;  // tid*4 dwords * 32 bits
#pragma unroll
    for (int wj = 0; wj < 4; ++wj) {
        uint32_t mm = words[wj];
        const uint32_t lb = local0 + (uint32_t)wj * 32u;
        while (mm) {
            const int bit = __ffs(mm) - 1;
            mm &= mm - 1;
            const uint32_t L = lb + (uint32_t)bit;  // bit index within chunk
            if (off < MAXK) {
                out_h[off] = h0 + (int)(L >> 11);
                out_w[off] = (int)(L & 2047u);
            }
            ++off;
        }
    }
}

extern "C" void kernel_launch(void* const* d_in, const int* in_sizes, int n_in,
                              void* d_out, int out_size, void* d_ws, size_t ws_size,
                              hipStream_t stream) {
    const float* scores = (const float*)d_in[0];
    int* out = (int*)d_out;
    uint32_t* flags = (uint32_t*)d_ws;  // [NBLK] status + [NBLK] ticket

    prefill<<<2048, 256, 0, stream>>>(out, flags);
    nms_fused<<<NBLK, 256, 0, stream>>>(scores, flags, out, out + MAXK);
}

// Round 7
// 69.334 us; speedup vs baseline: 1.0819x; 1.0093x over previous
//
#include <hip/hip_runtime.h>
#include <stdint.h>
#include <math.h>

// Problem constants (fixed by the reference)
#define BATCH 8
#define HH 2048
#define WW 2048
#define R 16                          // rows per chunk
#define NSTRIPS (HH / R)              // 128
#define NBLK (NSTRIPS * BATCH)        // 1024 chunks == 1024 blocks
#define CHUNK_DWORDS (R * WW / 32)    // 1024 mask dwords per chunk (4 KB LDS)
#define MAXK 2000000

#define STAT_AGG (1u << 30)
#define STAT_INC (2u << 30)
#define VALMASK  0x3FFFFFFFu

// ---------------- Pass 0: prefill output with -1, zero flags ---------------
__global__ __launch_bounds__(256) void prefill(int* __restrict__ out,
                                               uint32_t* __restrict__ flags) {
    const int4 neg = make_int4(-1, -1, -1, -1);
    const int stride = (int)(gridDim.x * 256);
    for (int i = (int)(blockIdx.x * 256 + threadIdx.x); i < (2 * MAXK) / 4; i += stride)
        ((int4*)out)[i] = neg;
    if (blockIdx.x == 0) {
        for (int i = threadIdx.x; i <= NBLK; i += 256) flags[i] = 0;
    }
}

// ---------------- Pass 1: fused mask + decoupled-lookback compaction -------
// One block per chunk (16 rows x 2048). Lookback status words are read with
// relaxed agent-scope LOADS (not RMWs): round-6 lesson — atomic RMW polling
// (~500K RMWs on one 4 KB region) serializes at the coherence point and
// throttled chip streaming BW to 1 TB/s.
__global__ __launch_bounds__(256) void nms_fused(const float* __restrict__ scores,
                                                 uint32_t* __restrict__ flags,  // [NBLK] status + [NBLK] ticket
                                                 int* __restrict__ out_h,
                                                 int* __restrict__ out_w) {
    __shared__ uint32_t lds_mask[CHUNK_DWORDS];  // 4 KB
    __shared__ int wsum[4];
    __shared__ int bcast0;
    __shared__ int vbid_s;

    const int tid  = threadIdx.x;
    const int lane = tid & 63;
    const int wv   = tid >> 6;

    // ---- ticket -> virtual chunk id (predecessors are guaranteed running) ----
    if (tid == 0) vbid_s = (int)atomicAdd(&flags[NBLK], 1u);
    __syncthreads();
    const int chunk = vbid_s;

    const int b     = chunk >> 7;            // / NSTRIPS (=128)
    const int strip = chunk & (NSTRIPS - 1);
    const int h0    = strip * R;
    const int c0    = wv * 512 + lane * 8;   // first owned column
    const float* colp = scores + (size_t)b * HH * WW + c0;
    const bool has_l = (c0 != 0);
    const bool has_r = (c0 != WW - 8);

    // ---- mask gen: register-rolling 5-row window ----
    float win[5][12];  // columns c0-2 .. c0+9

#define LOAD_ROW(PH, hrow)                                                    \
    do {                                                                      \
        const int h_ = (hrow);                                                \
        if ((unsigned)h_ < (unsigned)HH) {                                    \
            const float* p_ = colp + (size_t)h_ * WW;                         \
            float4 a_ = *(const float4*)(p_);                                 \
            float4 b_ = *(const float4*)(p_ + 4);                             \
            win[PH][2] = a_.x; win[PH][3] = a_.y;                             \
            win[PH][4] = a_.z; win[PH][5] = a_.w;                             \
            win[PH][6] = b_.x; win[PH][7] = b_.y;                             \
            win[PH][8] = b_.z; win[PH][9] = b_.w;                             \
            if (has_l) {                                                      \
                float2 hl_ = *(const float2*)(p_ - 2);                        \
                win[PH][0] = hl_.x; win[PH][1] = hl_.y;                       \
            } else { win[PH][0] = -INFINITY; win[PH][1] = -INFINITY; }        \
            if (has_r) {                                                      \
                float2 hr_ = *(const float2*)(p_ + 8);                        \
                win[PH][10] = hr_.x; win[PH][11] = hr_.y;                     \
            } else { win[PH][10] = -INFINITY; win[PH][11] = -INFINITY; }      \
        } else {                                                              \
            _Pragma("unroll")                                                 \
            for (int k_ = 0; k_ < 12; ++k_) win[PH][k_] = -INFINITY;          \
        }                                                                     \
    } while (0)

    LOAD_ROW(0, h0 - 2);
    LOAD_ROW(1, h0 - 1);
    LOAD_ROW(2, h0 + 0);
    LOAD_ROW(3, h0 + 1);

    uint8_t* mbytes = (uint8_t*)lds_mask;
    const int bytecol = wv * 64 + lane;  // 0..255

#pragma unroll
    for (int i = 0; i < R; ++i) {
        LOAD_ROW((4 + i) % 5, h0 + 2 + i);
        const int CEN = (2 + i) % 5;

        float v[12];
#pragma unroll
        for (int k = 0; k < 12; ++k)
            v[k] = fmaxf(fmaxf(fmaxf(win[0][k], win[1][k]),
                               fmaxf(win[2][k], win[3][k])), win[4][k]);
        float p[11];
#pragma unroll
        for (int k = 0; k < 11; ++k) p[k] = fmaxf(v[k], v[k + 1]);

        uint32_t byte = 0;
#pragma unroll
        for (int j = 0; j < 8; ++j) {
            const float hm = fmaxf(fmaxf(p[j], p[j + 2]), v[j + 4]);
            const float s  = win[CEN][j + 2];
            if ((s == hm) && (s > 0.0f)) byte |= (1u << j);
        }
        mbytes[i * 256 + bytecol] = (uint8_t)byte;
    }
#undef LOAD_ROW

    __syncthreads();

    // ---- per-thread 4 dwords, block reduce -> aggregate ----
    const uint4 m = ((const uint4*)lds_mask)[tid];
    const int pc = __popc(m.x) + __popc(m.y) + __popc(m.z) + __popc(m.w);

    int red = pc;
#pragma unroll
    for (int d = 32; d >= 1; d >>= 1) red += __shfl_down(red, d, 64);
    if (lane == 0) wsum[wv] = red;
    __syncthreads();
    const int agg = wsum[0] + wsum[1] + wsum[2] + wsum[3];

    if (tid == 0)
        __hip_atomic_store(&flags[chunk], STAT_AGG | (uint32_t)agg,
                           __ATOMIC_RELAXED, __HIP_MEMORY_SCOPE_AGENT);

    // ---- decoupled lookback (wave 0 only; relaxed agent-scope loads) ----
    if (wv == 0) {
        int exclusive = 0;
        int look = chunk;
        while (look > 0) {
            const int j = look - 1 - lane;  // lane 0 = nearest predecessor
            const bool valid = (j >= 0);
            uint32_t f;
            for (;;) {
                f = valid ? __hip_atomic_load(&flags[j], __ATOMIC_RELAXED,
                                              __HIP_MEMORY_SCOPE_AGENT)
                          : STAT_INC;  // j<0 => inclusive 0
                if (!__any((f >> 30) == 0)) break;
                __builtin_amdgcn_s_sleep(1);
            }
            const unsigned long long m2 = __ballot((f >> 30) == 2);
            if (m2) {
                const int stop = (int)__ffsll((unsigned long long)m2) - 1;
                int c = (lane <= stop) ? (int)(f & VALMASK) : 0;
#pragma unroll
                for (int d = 1; d < 64; d <<= 1) c += __shfl_xor(c, d, 64);
                exclusive += c;
                break;
            } else {
                int c = (int)(f & VALMASK);
#pragma unroll
                for (int d = 1; d < 64; d <<= 1) c += __shfl_xor(c, d, 64);
                exclusive += c;
                look -= 64;
            }
        }
        if (lane == 0) {
            bcast0 = exclusive;
            __hip_atomic_store(&flags[chunk], STAT_INC | (uint32_t)(exclusive + agg),
                               __ATOMIC_RELAXED, __HIP_MEMORY_SCOPE_AGENT);
        }
    }
    __syncthreads();
    const int chunk_base = bcast0;

    // ---- block exclusive scan + ordered scatter ----
    int incl = pc;
#pragma unroll
    for (int d = 1; d < 64; d <<= 1) {
        int n = __shfl_up(incl, d, 64);
        if (lane >= d) incl += n;
    }
    if (lane == 63) wsum[wv] = incl;  // safe: agg consumed before prior barrier
    __syncthreads();
    int wbase = 0;
    for (int i = 0; i < wv; ++i) wbase += wsum[i];

    int off = chunk_base + wbase + (incl - pc);

    uint32_t words[4] = {m.x, m.y, m.z, m.w};
    const uint32_t local0 = (uint32_t)tid * 128u;  // tid*4 dwords * 32 bits
#pragma unroll
    for (int wj = 0; wj < 4; ++wj) {
        uint32_t mm = words[wj];
        const uint32_t lb = local0 + (uint32_t)wj * 32u;
        while (mm) {
            const int bit = __ffs(mm) - 1;
            mm &= mm - 1;
            const uint32_t L = lb + (uint32_t)bit;  // bit index within chunk
            if (off < MAXK) {
                out_h[off] = h0 + (int)(L >> 11);
                out_w[off] = (int)(L & 2047u);
            }
            ++off;
        }
    }
}

extern "C" void kernel_launch(void* const* d_in, const int* in_sizes, int n_in,
                              void* d_out, int out_size, void* d_ws, size_t ws_size,
                              hipStream_t stream) {
    const float* scores = (const float*)d_in[0];
    int* out = (int*)d_out;
    uint32_t* flags = (uint32_t*)d_ws;  // [NBLK] status + [NBLK] ticket

    prefill<<<2048, 256, 0, stream>>>(out, flags);
    nms_fused<<<NBLK, 256, 0, stream>>>(scores, flags, out, out + MAXK);
}

// Round 8
// 43.137 us; speedup vs baseline: 1.7390x; 1.6073x over previous
//
#include <hip/hip_runtime.h>
#include <stdint.h>
#include <math.h>

// Problem constants (fixed by the reference)
#define BATCH 8
#define HH 2048
#define WW 2048
#define R 16                          // rows per chunk
#define NSTRIPS (HH / R)              // 128
#define NBLK (NSTRIPS * BATCH)        // 1024 mask chunks
#define BLK_WORDS (R * WW / 32)       // 1024 mask dwords per chunk
#define MAXK 2000000
#define FILLB 1024                    // fill blocks appended to kernel-1 grid
#define OUT_I4 ((2 * MAXK) / 4)       // 1,000,000 int4 slots across both planes

// ---------------- Kernel 1: mask + count (+ fused -1 prefill) --------------
// Blocks [0, NBLK): 5x5 separable local-max over a 16x2048 chunk,
//   register-rolling window, mask bytes -> global, fused popcount -> counts.
// Blocks [NBLK, NBLK+FILLB): grid-stride int4 fill of the whole [2, MAXK]
//   output with -1. No data dependency -> overlaps with mask streaming; the
//   compact kernel then only overwrites the head [0, total).
__global__ __launch_bounds__(256) void nms_mask_fill(const float* __restrict__ scores,
                                                     uint8_t* __restrict__ maskbytes,
                                                     int* __restrict__ counts,
                                                     int* __restrict__ out) {
    const int tid  = threadIdx.x;

    if (blockIdx.x >= NBLK) {
        // ---- prefill role ----
        const int fb = (int)blockIdx.x - NBLK;
        const int4 neg = make_int4(-1, -1, -1, -1);
        int4* o = (int4*)out;
        for (int i = fb * 256 + tid; i < OUT_I4; i += FILLB * 256)
            o[i] = neg;
        return;
    }

    // ---- mask + count role ----
    const int chunk = blockIdx.x;
    const int b     = chunk >> 7;            // / NSTRIPS (=128)
    const int strip = chunk & (NSTRIPS - 1);
    const int h0    = strip * R;
    const int lane  = tid & 63;
    const int wv    = tid >> 6;
    const int c0    = wv * 512 + lane * 8;   // first owned column
    const float* colp = scores + (size_t)b * HH * WW + c0;
    const bool has_l = (c0 != 0);
    const bool has_r = (c0 != WW - 8);

    float win[5][12];  // columns c0-2 .. c0+9

#define LOAD_ROW(PH, hrow)                                                    \
    do {                                                                      \
        const int h_ = (hrow);                                                \
        if ((unsigned)h_ < (unsigned)HH) {                                    \
            const float* p_ = colp + (size_t)h_ * WW;                         \
            float4 a_ = *(const float4*)(p_);                                 \
            float4 b_ = *(const float4*)(p_ + 4);                             \
            win[PH][2] = a_.x; win[PH][3] = a_.y;                             \
            win[PH][4] = a_.z; win[PH][5] = a_.w;                             \
            win[PH][6] = b_.x; win[PH][7] = b_.y;                             \
            win[PH][8] = b_.z; win[PH][9] = b_.w;                             \
            if (has_l) {                                                      \
                float2 hl_ = *(const float2*)(p_ - 2);                        \
                win[PH][0] = hl_.x; win[PH][1] = hl_.y;                       \
            } else { win[PH][0] = -INFINITY; win[PH][1] = -INFINITY; }        \
            if (has_r) {                                                      \
                float2 hr_ = *(const float2*)(p_ + 8);                        \
                win[PH][10] = hr_.x; win[PH][11] = hr_.y;                     \
            } else { win[PH][10] = -INFINITY; win[PH][11] = -INFINITY; }      \
        } else {                                                              \
            _Pragma("unroll")                                                 \
            for (int k_ = 0; k_ < 12; ++k_) win[PH][k_] = -INFINITY;          \
        }                                                                     \
    } while (0)

    LOAD_ROW(0, h0 - 2);
    LOAD_ROW(1, h0 - 1);
    LOAD_ROW(2, h0 + 0);
    LOAD_ROW(3, h0 + 1);

    int pc = 0;
    size_t outbyte = (((size_t)(b * HH + h0) * WW) + c0) >> 3;

#pragma unroll
    for (int i = 0; i < R; ++i) {
        LOAD_ROW((4 + i) % 5, h0 + 2 + i);
        const int CEN = (2 + i) % 5;

        float v[12];
#pragma unroll
        for (int k = 0; k < 12; ++k)
            v[k] = fmaxf(fmaxf(fmaxf(win[0][k], win[1][k]),
                               fmaxf(win[2][k], win[3][k])), win[4][k]);
        float p[11];
#pragma unroll
        for (int k = 0; k < 11; ++k) p[k] = fmaxf(v[k], v[k + 1]);

        uint32_t byte = 0;
#pragma unroll
        for (int j = 0; j < 8; ++j) {
            const float hm = fmaxf(fmaxf(p[j], p[j + 2]), v[j + 4]);
            const float s  = win[CEN][j + 2];
            if ((s == hm) && (s > 0.0f)) byte |= (1u << j);
        }
        maskbytes[outbyte] = (uint8_t)byte;
        outbyte += WW / 8;
        pc += __popc(byte);
    }
#undef LOAD_ROW

    // fused per-chunk count
#pragma unroll
    for (int d = 32; d >= 1; d >>= 1) pc += __shfl_down(pc, d, 64);
    __shared__ int wsum[4];
    if (lane == 0) wsum[wv] = pc;
    __syncthreads();
    if (tid == 0) counts[chunk] = wsum[0] + wsum[1] + wsum[2] + wsum[3];
}

// ---------------- Kernel 2: ordered compaction -----------------------------
// One block per chunk. Each block recomputes its own exclusive prefix from
// the 4 KB counts array (L2-hot, read by every block), then scatters (h,w).
__global__ __launch_bounds__(256) void compact(const uint32_t* __restrict__ bitmask,
                                               const int* __restrict__ counts,
                                               int* __restrict__ out_h,
                                               int* __restrict__ out_w) {
    const int chunk = blockIdx.x;
    const int tid   = threadIdx.x;
    const int lane  = tid & 63, wv = tid >> 6;

    // Exclusive prefix of counts[0..chunk) -- per-thread uint4, masked contrib.
    const uint4 c4 = ((const uint4*)counts)[tid];
    const int i0 = tid * 4;
    int contrib = 0;
    contrib += (i0 + 0 < chunk) ? (int)c4.x : 0;
    contrib += (i0 + 1 < chunk) ? (int)c4.y : 0;
    contrib += (i0 + 2 < chunk) ? (int)c4.z : 0;
    contrib += (i0 + 3 < chunk) ? (int)c4.w : 0;

    int red = contrib;
#pragma unroll
    for (int d = 32; d >= 1; d >>= 1) red += __shfl_down(red, d, 64);
    __shared__ int ws[4];
    __shared__ int base_s;
    if (lane == 0) ws[wv] = red;
    __syncthreads();
    if (tid == 0) base_s = ws[0] + ws[1] + ws[2] + ws[3];

    // Load this chunk's mask words (uint4 per thread).
    const uint32_t* mbase = bitmask + (size_t)chunk * BLK_WORDS;
    const uint4 m = ((const uint4*)mbase)[tid];
    const int pc = __popc(m.x) + __popc(m.y) + __popc(m.z) + __popc(m.w);

    // Block exclusive scan of pc.
    int incl = pc;
#pragma unroll
    for (int d = 1; d < 64; d <<= 1) {
        int n = __shfl_up(incl, d, 64);
        if (lane >= d) incl += n;
    }
    __shared__ int wsums[4];
    if (lane == 63) wsums[wv] = incl;
    __syncthreads();
    int wbase = 0;
    for (int i = 0; i < wv; ++i) wbase += wsums[i];

    const int h0 = (chunk & (NSTRIPS - 1)) * R;
    int off = base_s + wbase + (incl - pc);

    uint32_t words[4] = {m.x, m.y, m.z, m.w};
    const uint32_t local0 = (uint32_t)tid * 128u;  // tid*4 dwords * 32 bits
#pragma unroll
    for (int wj = 0; wj < 4; ++wj) {
        uint32_t mm = words[wj];
        const uint32_t lb = local0 + (uint32_t)wj * 32u;
        while (mm) {
            const int bit = __ffs(mm) - 1;
            mm &= mm - 1;
            const uint32_t L = lb + (uint32_t)bit;  // bit index within chunk
            if (off < MAXK) {
                out_h[off] = h0 + (int)(L >> 11);
                out_w[off] = (int)(L & 2047u);
            }
            ++off;
        }
    }
}

extern "C" void kernel_launch(void* const* d_in, const int* in_sizes, int n_in,
                              void* d_out, int out_size, void* d_ws, size_t ws_size,
                              hipStream_t stream) {
    const float* scores = (const float*)d_in[0];
    int* out = (int*)d_out;

    uint32_t* bitmask = (uint32_t*)d_ws;                          // 4 MB
    int* counts = (int*)((char*)d_ws + (size_t)NBLK * BLK_WORDS * 4);  // NBLK ints

    nms_mask_fill<<<NBLK + FILLB, 256, 0, stream>>>(scores, (uint8_t*)bitmask,
                                                    counts, out);
    compact<<<NBLK, 256, 0, stream>>>(bitmask, counts, out, out + MAXK);
}